// Round 2
// baseline (9.410 us; speedup 1.0000x reference)
//
#include <hip/hip_runtime.h>

#define WIDTH 64
#define HW (WIDTH * WIDTH)   // 4096
#define BATCH 16
#define NTHREADS (HW * BATCH / 4)   // 16384 threads, one float4 batch-quad each

// y[(yo,xo), b] = sigmoid( sum over (dy,dx) in [-1,1]^2 of
//                          w[k][(yo-dy,xo-dx)] * x[(yo-dy,xo-dx), b] )
// k = (dx+1)*3 + (dy+1)  (Python: dx outer, dy inner).
// network[] input is a deterministic shift mask — never read.
__global__ __launch_bounds__(128) void BCNLayer_kernel(
        const float* __restrict__ x,      // (HW, BATCH)
        const float* __restrict__ w,      // (K, HW, 1)
        float* __restrict__ out) {        // (HW, BATCH)
    int t = blockIdx.x * blockDim.x + threadIdx.x;
    if (t >= NTHREADS) return;
    int q  = t & 3;            // batch quad (b = 4q..4q+3)
    int i  = t >> 2;           // output neuron linear index
    int xo = i & (WIDTH - 1);
    int yo = i >> 6;

    float4 acc = make_float4(0.f, 0.f, 0.f, 0.f);
#pragma unroll
    for (int dx = -1; dx <= 1; ++dx) {
#pragma unroll
        for (int dy = -1; dy <= 1; ++dy) {
            int xi = xo - dx;
            int yi = yo - dy;
            if ((unsigned)xi < (unsigned)WIDTH && (unsigned)yi < (unsigned)WIDTH) {
                int k = (dx + 1) * 3 + (dy + 1);
                int j = xi + WIDTH * yi;
                float wk = w[k * HW + j];
                float4 xv = *reinterpret_cast<const float4*>(&x[j * BATCH + q * 4]);
                acc.x = fmaf(wk, xv.x, acc.x);
                acc.y = fmaf(wk, xv.y, acc.y);
                acc.z = fmaf(wk, xv.z, acc.z);
                acc.w = fmaf(wk, xv.w, acc.w);
            }
        }
    }
    float4 r;
    r.x = 1.0f / (1.0f + __expf(-acc.x));
    r.y = 1.0f / (1.0f + __expf(-acc.y));
    r.z = 1.0f / (1.0f + __expf(-acc.z));
    r.w = 1.0f / (1.0f + __expf(-acc.w));
    *reinterpret_cast<float4*>(&out[t * 4]) = r;
}

extern "C" void kernel_launch(void* const* d_in, const int* in_sizes, int n_in,
                              void* d_out, int out_size, void* d_ws, size_t ws_size,
                              hipStream_t stream) {
    const float* x = (const float*)d_in[0];   // (HW, BATCH) f32
    const float* w = (const float*)d_in[1];   // (K, HW, 1) f32
    // d_in[2] = network, deterministic shift masks — unused.
    float* out = (float*)d_out;

    int threads = 128;
    int blocks = (NTHREADS + threads - 1) / threads;  // 128 blocks
    BCNLayer_kernel<<<blocks, threads, 0, stream>>>(x, w, out);
}